// Round 10
// baseline (159.462 us; speedup 1.0000x reference)
//
#include <hip/hip_runtime.h>
#include <cstdint>
#include <cstddef>

typedef __bf16 bf16;
typedef __bf16 bf16x4 __attribute__((ext_vector_type(4)));
typedef __bf16 bf16x8 __attribute__((ext_vector_type(8)));
typedef float f32x4 __attribute__((ext_vector_type(4)));
typedef float f32x16 __attribute__((ext_vector_type(16)));

typedef const __attribute__((address_space(1))) void* gas_ptr;
typedef __attribute__((address_space(3))) void* las_ptr;

#define GLOAD_LDS16(g, l) __builtin_amdgcn_global_load_lds((gas_ptr)(g), (las_ptr)(l), 16, 0, 0)

// ---------------- f32 -> bf16 convert (vectorized, grid-stride) ----------------
__global__ void cvt_f32_bf16(const float* __restrict__ in, bf16* __restrict__ out, int n4) {
  int i = blockIdx.x * blockDim.x + threadIdx.x;
  int stride = gridDim.x * blockDim.x;
  for (; i < n4; i += stride) {
    float4 v = reinterpret_cast<const float4*>(in)[i];
    bf16x4 o;
    o[0] = (bf16)v.x; o[1] = (bf16)v.y; o[2] = (bf16)v.z; o[3] = (bf16)v.w;
    reinterpret_cast<bf16x4*>(out)[i] = o;
  }
}

// ---------------- GEMM: C[M,N] = A[M,K] * B[N,K]^T  (both K-contiguous) --------
// r10 rebuild mirroring the attn r9 recipe:
//  * fragment-order LDS: slot r (r=0..7) lane l holds A[r*16+(l&15)][k0+(l>>4)*8..+8]
//    -> ds_read_b128 at r*1024B + l*16B is lane-linear: ZERO bank conflicts
//    (old [128][32] rows were 64B apart -> 8-way conflict, 3.5M cycles).
//  * double-buffered global_load_lds (gathered SOURCE, lane-linear dest):
//    stage(next) -> compute(cur) -> vmcnt(0)+barrier. Old code exposed the
//    full staging latency every K-step (stage->sync->compute).
//  * MODE 0 writes plain row-major bf16 C (no scatter); MODE 1 f32 + bias.
//  * XCD-bijective swizzle (requires nwg % 8 == 0: 1152 / 384 both OK).
template <int MODE>
__global__ __launch_bounds__(256, 3) void gemm_bt(
    const bf16* __restrict__ A, const bf16* __restrict__ B,
    int M, int N, int K,
    bf16* __restrict__ outb, float* __restrict__ outf,
    const float* __restrict__ bias) {
  constexpr int BK = 32;
  __shared__ bf16 ldsA[2][4096];   // 8 slots x 512 elems, double-buffered
  __shared__ bf16 ldsB[2][4096];
  const int tid = threadIdx.x;
  const int l = tid & 63;
  const int w = tid >> 6;
  const int wr = w >> 1, wc = w & 1;
  const int lr = l & 15, lg = l >> 4;

  // XCD-bijective swizzle: XCD(orig)=orig%8 gets contiguous tile chunk.
  const int gx = gridDim.x, nwg = gx * gridDim.y;
  int bid = blockIdx.y * gx + blockIdx.x;
  bid = (bid & 7) * (nwg >> 3) + (bid >> 3);
  const int brow = (bid % gx) * 128;
  const int bcol = (bid / gx) * 128;

  // staging sources: wave w stages slots {w, 4+w} of A and B.
  // slot r, lane l <- [base + r*16 + (l&15)]-th row, col (l>>4)*8 (+k0)
  const bf16* sa0 = A + (size_t)(brow + w * 16 + lr) * K + lg * 8;
  const bf16* sa1 = sa0 + (size_t)64 * K;
  const bf16* sb0 = B + (size_t)(bcol + w * 16 + lr) * K + lg * 8;
  const bf16* sb1 = sb0 + (size_t)64 * K;
  const int d0 = w * 512 + l * 8;          // LDS elem offset, slot w
  const int d1 = (4 + w) * 512 + l * 8;    // slot 4+w

  f32x4 acc[4][4] = {};

  // prologue: stage k0=0 into buffer 0
  GLOAD_LDS16(sa0, &ldsA[0][d0]);
  GLOAD_LDS16(sa1, &ldsA[0][d1]);
  GLOAD_LDS16(sb0, &ldsB[0][d0]);
  GLOAD_LDS16(sb1, &ldsB[0][d1]);
  asm volatile("s_waitcnt vmcnt(0)" ::: "memory");
  __syncthreads();

  int p = 0;
  for (int k0 = 0; k0 < K; k0 += BK) {
    // stage NEXT K-step (async; lands under this step's compute)
    if (k0 + BK < K) {
      GLOAD_LDS16(sa0 + (k0 + BK), &ldsA[p ^ 1][d0]);
      GLOAD_LDS16(sa1 + (k0 + BK), &ldsA[p ^ 1][d1]);
      GLOAD_LDS16(sb0 + (k0 + BK), &ldsB[p ^ 1][d0]);
      GLOAD_LDS16(sb1 + (k0 + BK), &ldsB[p ^ 1][d1]);
    }
    bf16x8 af[4], bfr[4];
#pragma unroll
    for (int mi = 0; mi < 4; mi++)
      af[mi] = *reinterpret_cast<const bf16x8*>(&ldsA[p][(wr * 4 + mi) * 512 + l * 8]);
#pragma unroll
    for (int ni = 0; ni < 4; ni++)
      bfr[ni] = *reinterpret_cast<const bf16x8*>(&ldsB[p][(wc * 4 + ni) * 512 + l * 8]);
#pragma unroll
    for (int mi = 0; mi < 4; mi++)
#pragma unroll
      for (int ni = 0; ni < 4; ni++)
        acc[mi][ni] = __builtin_amdgcn_mfma_f32_16x16x32_bf16(af[mi], bfr[ni], acc[mi][ni], 0, 0, 0);
    asm volatile("s_waitcnt vmcnt(0)" ::: "memory");
    __syncthreads();
    p ^= 1;
  }

  // epilogue: C frag mapping col = lr, row = lg*4 + r  (branch-free row-major)
#pragma unroll
  for (int mi = 0; mi < 4; mi++) {
#pragma unroll
    for (int r = 0; r < 4; r++) {
      const int m = brow + wr * 64 + mi * 16 + lg * 4 + r;
#pragma unroll
      for (int ni = 0; ni < 4; ni++) {
        const int e = bcol + wc * 64 + ni * 16 + lr;
        const float v = acc[mi][ni][r];
        if (MODE == 1) {
          outf[(size_t)m * N + e] = v + bias[e];
        } else {
          outb[(size_t)m * N + e] = (bf16)v;
        }
      }
    }
  }
}

// ---------------- V transpose: qkv cols [1536..2304) -> vtb[96][64][1024] -----
// block = (head bh, 64-wide n tile). LDS d-major [64][72] (pitch 72 keeps
// phase-2 b128 reads 16B-aligned & clean; phase-1 scalar writes are cheap).
__global__ __launch_bounds__(256) void vtrans(const bf16* __restrict__ qkv,
                                              bf16* __restrict__ vtb) {
  __shared__ bf16 t[64 * 72];
  const int bh = blockIdx.x;          // 0..95
  const int b = bh / 12, h = bh % 12;
  const int nt = blockIdx.y;          // 0..15
  const int tid = threadIdx.x;
#pragma unroll
  for (int it = 0; it < 2; it++) {
    const int item = tid + it * 256;  // 0..511
    const int nl = item >> 3, c = item & 7;
    bf16x8 v = *reinterpret_cast<const bf16x8*>(
        &qkv[(size_t)(b * 1024 + nt * 64 + nl) * 2304 + 1536 + h * 64 + c * 8]);
#pragma unroll
    for (int j = 0; j < 8; j++) t[(c * 8 + j) * 72 + nl] = v[j];
  }
  __syncthreads();
#pragma unroll
  for (int it = 0; it < 2; it++) {
    const int item = tid + it * 256;
    const int d = item >> 3, c2 = item & 7;
    bf16x8 v = *reinterpret_cast<const bf16x8*>(&t[d * 72 + c2 * 8]);
    *reinterpret_cast<bf16x8*>(
        &vtb[(size_t)bh * 65536 + d * 1024 + nt * 64 + c2 * 8]) = v;
  }
}

// ---------------- Flash attention: LDS-staged, fragment-order layout ----------
// Q,K read directly from qkv[8192][2304] (cols: Q h*64.., K 768+h*64..);
// V^T from vtb[96][64][1024]. Head-private 64B lines -> XCD L2 pinning intact.
// Structure identical to the r9 kernel that collapsed attn 99.5 -> ~20 us.
__global__ __launch_bounds__(256, 3) void attn_kernel(
    const bf16* __restrict__ QKV, const bf16* __restrict__ Vt,
    bf16* __restrict__ Out) {
  __shared__ bf16 Kb[2][4096];   // 8KB per buffer, fragment-order
  __shared__ bf16 Vb[2][4096];
  const int tid = threadIdx.x;
  const int l = tid & 63;
  const int w = tid >> 6;
  const int ql = l & 31;
  const int hi = l >> 5;
  const int bh = blockIdx.x;       // 0..95 (head-major -> XCD pinning)
  const int b = bh / 12, h = bh % 12;
  const int q0 = blockIdx.y * 128 + w * 32;
  const bf16* Vh = Vt + (size_t)bh * 65536;
  constexpr float L2E = 1.4426950408889634f;

  // Staging map: round j in {0,1}, wave w stages K frag slot r = j*4+w.
  const int kdst0 = (0 * 4 + w) * 512 + l * 8;
  const int kdst1 = (1 * 4 + w) * 512 + l * 8;
  const bf16* ksrc0 = QKV + (size_t)(b * 1024 + ql) * 2304 + 768 + h * 64 + w * 16 + hi * 8;
  const bf16* ksrc1 = ksrc0 + (size_t)32 * 2304;
  const bf16* vsrc0 = Vh + (size_t)((w & 1) * 32 + ql) * 1024 + ((0 * 4 + w) >> 1) * 16 + hi * 8;
  const bf16* vsrc1 = Vh + (size_t)((w & 1) * 32 + ql) * 1024 + ((1 * 4 + w) >> 1) * 16 + hi * 8;

  // Q as B-operand of S^T = K.Q^T : col=q=lane&31, contraction d = s*16+hi*8+j
  const bf16* Qrow = QKV + (size_t)(b * 1024 + q0 + ql) * 2304 + h * 64;
  bf16x8 qf[4];
#pragma unroll
  for (int s = 0; s < 4; s++)
    qf[s] = *reinterpret_cast<const bf16x8*>(&Qrow[s * 16 + hi * 8]);

  f32x16 o[2] = {};
  float ls0 = 0.f, ls1 = 0.f, ls2 = 0.f, ls3 = 0.f;

  // ---- prologue: stage tile 0 into buffer 0 ----
  GLOAD_LDS16(ksrc0, &Kb[0][kdst0]);
  GLOAD_LDS16(ksrc1, &Kb[0][kdst1]);
  GLOAD_LDS16(vsrc0, &Vb[0][kdst0]);
  GLOAD_LDS16(vsrc1, &Vb[0][kdst1]);
  asm volatile("s_waitcnt vmcnt(0)" ::: "memory");
  __syncthreads();

  int p = 0;
  for (int it = 0; it < 16; ++it) {
    const int kt = it * 64;
    // ---- stage NEXT tile into buffer p^1 (async; lands during compute) ----
    if (it < 15) {
      GLOAD_LDS16(ksrc0 + (size_t)(kt + 64) * 2304, &Kb[p ^ 1][kdst0]);
      GLOAD_LDS16(ksrc1 + (size_t)(kt + 64) * 2304, &Kb[p ^ 1][kdst1]);
      GLOAD_LDS16(vsrc0 + (kt + 64), &Vb[p ^ 1][kdst0]);
      GLOAD_LDS16(vsrc1 + (kt + 64), &Vb[p ^ 1][kdst1]);
    }

    // ---- K fragments (lane-linear ds_read_b128, conflict-free) + QK^T ----
    bf16x8 kf[8];
#pragma unroll
    for (int r = 0; r < 8; r++)
      kf[r] = *reinterpret_cast<const bf16x8*>(&Kb[p][r * 512 + l * 8]);
    f32x16 st0 = {}, st1 = {};
    __builtin_amdgcn_s_setprio(1);
#pragma unroll
    for (int s = 0; s < 4; s++) {
      st0 = __builtin_amdgcn_mfma_f32_32x32x16_bf16(kf[s], qf[s], st0, 0, 0, 0);
      st1 = __builtin_amdgcn_mfma_f32_32x32x16_bf16(kf[4 + s], qf[s], st1, 0, 0, 0);
    }
    __builtin_amdgcn_s_setprio(0);

    // ---- softmax without max: p = exp2(s*log2e); per-lane partial sums ----
#pragma unroll
    for (int r = 0; r < 16; r++) {
      float a0 = st0[r] * L2E, a1 = st1[r] * L2E;
      float e0, e1;
      asm("v_exp_f32 %0, %1" : "=v"(e0) : "v"(a0));
      asm("v_exp_f32 %0, %1" : "=v"(e1) : "v"(a1));
      st0[r] = e0; st1[r] = e1;
    }
#pragma unroll
    for (int r = 0; r < 16; r += 2) {
      ls0 += st0[r]; ls1 += st0[r + 1];
      ls2 += st1[r]; ls3 += st1[r + 1];
    }

    // ---- P^T -> bf16 B-fragments (st dies here) ----
    bf16x8 pfv[4];
#pragma unroll
    for (int t = 0; t < 4; t++) {
      const int c8 = (t & 1) * 8;
      const f32x16& sv = (t < 2) ? st0 : st1;
      uint32_t wA0, wA1, wB0, wB1;
      asm("v_cvt_pk_bf16_f32 %0, %1, %2" : "=v"(wA0) : "v"(sv[c8 + 0]), "v"(sv[c8 + 1]));
      asm("v_cvt_pk_bf16_f32 %0, %1, %2" : "=v"(wA1) : "v"(sv[c8 + 2]), "v"(sv[c8 + 3]));
      asm("v_cvt_pk_bf16_f32 %0, %1, %2" : "=v"(wB0) : "v"(sv[c8 + 4]), "v"(sv[c8 + 5]));
      asm("v_cvt_pk_bf16_f32 %0, %1, %2" : "=v"(wB1) : "v"(sv[c8 + 6]), "v"(sv[c8 + 7]));
      asm("v_permlane32_swap_b32 %0, %1" : "+v"(wA0), "+v"(wB0));
      asm("v_permlane32_swap_b32 %0, %1" : "+v"(wA1), "+v"(wB1));
      union { uint32_t u[4]; bf16x8 v; } pf;
      pf.u[0] = wA0; pf.u[1] = wA1; pf.u[2] = wB0; pf.u[3] = wB1;
      pfv[t] = pf.v;
    }

    // ---- V fragments (lane-linear) + PV ----
    bf16x8 vf[8];
#pragma unroll
    for (int r = 0; r < 8; r++)
      vf[r] = *reinterpret_cast<const bf16x8*>(&Vb[p][r * 512 + l * 8]);
    __builtin_amdgcn_s_setprio(1);
#pragma unroll
    for (int t = 0; t < 4; t++) {
      o[0] = __builtin_amdgcn_mfma_f32_32x32x16_bf16(vf[t * 2 + 0], pfv[t], o[0], 0, 0, 0);
      o[1] = __builtin_amdgcn_mfma_f32_32x32x16_bf16(vf[t * 2 + 1], pfv[t], o[1], 0, 0, 0);
    }
    __builtin_amdgcn_s_setprio(0);

    // ---- next-tile staging must be complete; all waves done with cur ----
    asm volatile("s_waitcnt vmcnt(0)" ::: "memory");
    __syncthreads();
    p ^= 1;
  }

  // ---- normalize + store: Out[b, q0+ql, h*64 + d], 8B vector stores ----
  float lsum = (ls0 + ls1) + (ls2 + ls3);
  lsum += __shfl_xor(lsum, 32);
  const float rl = 1.0f / lsum;
  bf16* orow = Out + (size_t)(b * 1024 + q0 + ql) * 768 + h * 64;
#pragma unroll
  for (int dh = 0; dh < 2; dh++)
#pragma unroll
    for (int rq = 0; rq < 4; rq++) {
      union { ushort us[4]; uint2 v; } pk;
#pragma unroll
      for (int i = 0; i < 4; i++) {
        const bf16 hv = (bf16)(o[dh][rq * 4 + i] * rl);
        pk.us[i] = __builtin_bit_cast(ushort, hv);
      }
      *reinterpret_cast<uint2*>(&orow[dh * 32 + rq * 8 + hi * 4]) = pk.v;
    }
}

// ---------------- launch ------------------------------------------------------
extern "C" void kernel_launch(void* const* d_in, const int* in_sizes, int n_in,
                              void* d_out, int out_size, void* d_ws, size_t ws_size,
                              hipStream_t stream) {
  const float* x = (const float*)d_in[0];
  const float* w_qkv = (const float*)d_in[1];
  const float* w_fc = (const float*)d_in[2];
  const float* b_fc = (const float*)d_in[3];
  float* out = (float*)d_out;
  char* ws = (char*)d_ws;

  bf16* xb = (bf16*)(ws);                    // 8192x768   (dead after gemm<0>)
  bf16* vtb = (bf16*)(ws);                   // 96x64x1024 (aliases xb -- safe)
  bf16* wqkb = (bf16*)(ws + 12582912);       // 2304x768
  bf16* wfcb = (bf16*)(ws + 16121856);       // 768x768
  bf16* qkvb = (bf16*)(ws + 17301504);       // 8192x2304 = 37748736 B
  bf16* aob = (bf16*)(ws + 55050240);        // 8192x768
  // total ws use: 67633152 B (same footprint as r9)

  cvt_f32_bf16<<<2048, 256, 0, stream>>>(x, xb, 6291456 / 4);
  cvt_f32_bf16<<<1728, 256, 0, stream>>>(w_qkv, wqkb, 1769472 / 4);
  cvt_f32_bf16<<<576, 256, 0, stream>>>(w_fc, wfcb, 589824 / 4);

  gemm_bt<0><<<dim3(64, 18), 256, 0, stream>>>(xb, wqkb, 8192, 2304, 768,
                                               qkvb, nullptr, nullptr);

  vtrans<<<dim3(96, 16), 256, 0, stream>>>(qkvb, vtb);

  attn_kernel<<<dim3(96, 8), 256, 0, stream>>>(qkvb, vtb, aob);

  gemm_bt<1><<<dim3(64, 6), 256, 0, stream>>>(aob, wfcb, 8192, 768, 768,
                                              nullptr, out, b_fc);
}

// Round 11
// 156.363 us; speedup vs baseline: 1.0198x; 1.0198x over previous
//
#include <hip/hip_runtime.h>
#include <cstdint>
#include <cstddef>

typedef __bf16 bf16;
typedef __bf16 bf16x4 __attribute__((ext_vector_type(4)));
typedef __bf16 bf16x8 __attribute__((ext_vector_type(8)));
typedef float f32x4 __attribute__((ext_vector_type(4)));
typedef float f32x16 __attribute__((ext_vector_type(16)));

typedef const __attribute__((address_space(1))) void* gas_ptr;
typedef __attribute__((address_space(3))) void* las_ptr;

#define GLOAD_LDS16(g, l) __builtin_amdgcn_global_load_lds((gas_ptr)(g), (las_ptr)(l), 16, 0, 0)

// ---------------- f32 -> bf16 convert (vectorized, grid-stride) ----------------
__global__ void cvt_f32_bf16(const float* __restrict__ in, bf16* __restrict__ out, int n4) {
  int i = blockIdx.x * blockDim.x + threadIdx.x;
  int stride = gridDim.x * blockDim.x;
  for (; i < n4; i += stride) {
    float4 v = reinterpret_cast<const float4*>(in)[i];
    bf16x4 o;
    o[0] = (bf16)v.x; o[1] = (bf16)v.y; o[2] = (bf16)v.z; o[3] = (bf16)v.w;
    reinterpret_cast<bf16x4*>(out)[i] = o;
  }
}

// ---------------- GEMM: C[M,N] = A[M,K] * B[N,K]^T  (both K-contiguous) --------
// r11: two fixes on the r10 structure (fragment-order LDS kept, 0 conflicts):
//  * XCD swizzle was COLUMN-chunk (each XCD pulled ALL of A: FETCH 86MB).
//    Now ROW-chunk per XCD (A panel 1.57MB stays in its L2), col-major
//    traversal within the chunk (B col panel reused 8x back-to-back).
//  * 2-phase vmcnt(0) drained the pipe every K-step (compute ~200cy <<
//    load latency). Now 3-buffer 2-deep: wait vmcnt(4) -> barrier ->
//    stage(k+2*BK) -> compute(k). Each load gets ~2 compute phases of cover.
//    Tail stages a dummy (clamped kn) to keep the vmcnt count uniform.
template <int MODE>
__global__ __launch_bounds__(256, 3) void gemm_bt(
    const bf16* __restrict__ A, const bf16* __restrict__ B,
    int M, int N, int K,
    bf16* __restrict__ outb, float* __restrict__ outf,
    const float* __restrict__ bias) {
  constexpr int BK = 32;
  __shared__ bf16 ldsA[3][4096];   // 8 slots x 512 elems, triple-buffered
  __shared__ bf16 ldsB[3][4096];
  const int tid = threadIdx.x;
  const int l = tid & 63;
  const int w = tid >> 6;
  const int wr = w >> 1, wc = w & 1;
  const int lr = l & 15, lg = l >> 4;

  // XCD row-chunk swizzle (needs gx%8==0 and nwg%8==0; 64x18 and 64x6 both OK)
  const int gx = gridDim.x;
  const int bid = blockIdx.y * gx + blockIdx.x;
  const int xcd = bid & 7, c = bid >> 3, rpx = gx >> 3;   // rpx = 8
  const int brow = (xcd * rpx + (c & (rpx - 1))) * 128;
  const int bcol = (c / rpx) * 128;

  // staging sources: wave w stages slots {w, 4+w} of A and B.
  // slot r, lane l <- row (base + r*16 + (l&15)), col (l>>4)*8 (+k0)
  const bf16* sa0 = A + (size_t)(brow + w * 16 + lr) * K + lg * 8;
  const bf16* sa1 = sa0 + (size_t)64 * K;
  const bf16* sb0 = B + (size_t)(bcol + w * 16 + lr) * K + lg * 8;
  const bf16* sb1 = sb0 + (size_t)64 * K;
  const int d0 = w * 512 + l * 8;          // LDS elem offset, slot w
  const int d1 = (4 + w) * 512 + l * 8;    // slot 4+w

  f32x4 acc[4][4] = {};

  // prologue: stage k0=0 -> buf0, k0=BK -> buf1  (8 loads in flight per wave)
  GLOAD_LDS16(sa0, &ldsA[0][d0]);
  GLOAD_LDS16(sa1, &ldsA[0][d1]);
  GLOAD_LDS16(sb0, &ldsB[0][d0]);
  GLOAD_LDS16(sb1, &ldsB[0][d1]);
  GLOAD_LDS16(sa0 + BK, &ldsA[1][d0]);
  GLOAD_LDS16(sa1 + BK, &ldsA[1][d1]);
  GLOAD_LDS16(sb0 + BK, &ldsB[1][d0]);
  GLOAD_LDS16(sb1 + BK, &ldsB[1][d1]);

  int p = 0;
  for (int k0 = 0; k0 < K; k0 += BK) {
    // wait: the newest 4 loads (next buffer) may stay in flight; everything
    // older -- including THIS buffer's 4 -- is complete. Then barrier makes
    // that true across all waves of the block.
    asm volatile("s_waitcnt vmcnt(4)" ::: "memory");
    __syncthreads();

    // stage k0+2*BK into the buffer freed at the barrier (dummy on tail)
    int kn = k0 + 2 * BK;
    if (kn >= K) kn = k0;
    const int pt = (p >= 1) ? p - 1 : 2;   // (p+2)%3
    GLOAD_LDS16(sa0 + kn, &ldsA[pt][d0]);
    GLOAD_LDS16(sa1 + kn, &ldsA[pt][d1]);
    GLOAD_LDS16(sb0 + kn, &ldsB[pt][d0]);
    GLOAD_LDS16(sb1 + kn, &ldsB[pt][d1]);

    bf16x8 af[4], bfr[4];
#pragma unroll
    for (int mi = 0; mi < 4; mi++)
      af[mi] = *reinterpret_cast<const bf16x8*>(&ldsA[p][(wr * 4 + mi) * 512 + l * 8]);
#pragma unroll
    for (int ni = 0; ni < 4; ni++)
      bfr[ni] = *reinterpret_cast<const bf16x8*>(&ldsB[p][(wc * 4 + ni) * 512 + l * 8]);
    __builtin_amdgcn_s_setprio(1);
#pragma unroll
    for (int mi = 0; mi < 4; mi++)
#pragma unroll
      for (int ni = 0; ni < 4; ni++)
        acc[mi][ni] = __builtin_amdgcn_mfma_f32_16x16x32_bf16(af[mi], bfr[ni], acc[mi][ni], 0, 0, 0);
    __builtin_amdgcn_s_setprio(0);
    p = (p == 2) ? 0 : p + 1;
  }

  // epilogue: C frag mapping col = lr, row = lg*4 + r  (branch-free row-major)
#pragma unroll
  for (int mi = 0; mi < 4; mi++) {
#pragma unroll
    for (int r = 0; r < 4; r++) {
      const int m = brow + wr * 64 + mi * 16 + lg * 4 + r;
#pragma unroll
      for (int ni = 0; ni < 4; ni++) {
        const int e = bcol + wc * 64 + ni * 16 + lr;
        const float v = acc[mi][ni][r];
        if (MODE == 1) {
          outf[(size_t)m * N + e] = v + bias[e];
        } else {
          outb[(size_t)m * N + e] = (bf16)v;
        }
      }
    }
  }
}

// ---------------- V transpose: qkv cols [1536..2304) -> vtb[96][64][1024] -----
__global__ __launch_bounds__(256) void vtrans(const bf16* __restrict__ qkv,
                                              bf16* __restrict__ vtb) {
  __shared__ bf16 t[64 * 72];
  const int bh = blockIdx.x;          // 0..95
  const int b = bh / 12, h = bh % 12;
  const int nt = blockIdx.y;          // 0..15
  const int tid = threadIdx.x;
#pragma unroll
  for (int it = 0; it < 2; it++) {
    const int item = tid + it * 256;  // 0..511
    const int nl = item >> 3, c = item & 7;
    bf16x8 v = *reinterpret_cast<const bf16x8*>(
        &qkv[(size_t)(b * 1024 + nt * 64 + nl) * 2304 + 1536 + h * 64 + c * 8]);
#pragma unroll
    for (int j = 0; j < 8; j++) t[(c * 8 + j) * 72 + nl] = v[j];
  }
  __syncthreads();
#pragma unroll
  for (int it = 0; it < 2; it++) {
    const int item = tid + it * 256;
    const int d = item >> 3, c2 = item & 7;
    bf16x8 v = *reinterpret_cast<const bf16x8*>(&t[d * 72 + c2 * 8]);
    *reinterpret_cast<bf16x8*>(
        &vtb[(size_t)bh * 65536 + d * 1024 + nt * 64 + c2 * 8]) = v;
  }
}

// ---------------- Flash attention: LDS-staged, fragment-order layout ----------
// (unchanged from r9/r10 -- this structure took attn 99.5 -> ~20 us)
__global__ __launch_bounds__(256, 3) void attn_kernel(
    const bf16* __restrict__ QKV, const bf16* __restrict__ Vt,
    bf16* __restrict__ Out) {
  __shared__ bf16 Kb[2][4096];   // 8KB per buffer, fragment-order
  __shared__ bf16 Vb[2][4096];
  const int tid = threadIdx.x;
  const int l = tid & 63;
  const int w = tid >> 6;
  const int ql = l & 31;
  const int hi = l >> 5;
  const int bh = blockIdx.x;       // 0..95 (head-major -> XCD pinning)
  const int b = bh / 12, h = bh % 12;
  const int q0 = blockIdx.y * 128 + w * 32;
  const bf16* Vh = Vt + (size_t)bh * 65536;
  constexpr float L2E = 1.4426950408889634f;

  const int kdst0 = (0 * 4 + w) * 512 + l * 8;
  const int kdst1 = (1 * 4 + w) * 512 + l * 8;
  const bf16* ksrc0 = QKV + (size_t)(b * 1024 + ql) * 2304 + 768 + h * 64 + w * 16 + hi * 8;
  const bf16* ksrc1 = ksrc0 + (size_t)32 * 2304;
  const bf16* vsrc0 = Vh + (size_t)((w & 1) * 32 + ql) * 1024 + ((0 * 4 + w) >> 1) * 16 + hi * 8;
  const bf16* vsrc1 = Vh + (size_t)((w & 1) * 32 + ql) * 1024 + ((1 * 4 + w) >> 1) * 16 + hi * 8;

  const bf16* Qrow = QKV + (size_t)(b * 1024 + q0 + ql) * 2304 + h * 64;
  bf16x8 qf[4];
#pragma unroll
  for (int s = 0; s < 4; s++)
    qf[s] = *reinterpret_cast<const bf16x8*>(&Qrow[s * 16 + hi * 8]);

  f32x16 o[2] = {};
  float ls0 = 0.f, ls1 = 0.f, ls2 = 0.f, ls3 = 0.f;

  GLOAD_LDS16(ksrc0, &Kb[0][kdst0]);
  GLOAD_LDS16(ksrc1, &Kb[0][kdst1]);
  GLOAD_LDS16(vsrc0, &Vb[0][kdst0]);
  GLOAD_LDS16(vsrc1, &Vb[0][kdst1]);
  asm volatile("s_waitcnt vmcnt(0)" ::: "memory");
  __syncthreads();

  int p = 0;
  for (int it = 0; it < 16; ++it) {
    const int kt = it * 64;
    if (it < 15) {
      GLOAD_LDS16(ksrc0 + (size_t)(kt + 64) * 2304, &Kb[p ^ 1][kdst0]);
      GLOAD_LDS16(ksrc1 + (size_t)(kt + 64) * 2304, &Kb[p ^ 1][kdst1]);
      GLOAD_LDS16(vsrc0 + (kt + 64), &Vb[p ^ 1][kdst0]);
      GLOAD_LDS16(vsrc1 + (kt + 64), &Vb[p ^ 1][kdst1]);
    }

    bf16x8 kf[8];
#pragma unroll
    for (int r = 0; r < 8; r++)
      kf[r] = *reinterpret_cast<const bf16x8*>(&Kb[p][r * 512 + l * 8]);
    f32x16 st0 = {}, st1 = {};
    __builtin_amdgcn_s_setprio(1);
#pragma unroll
    for (int s = 0; s < 4; s++) {
      st0 = __builtin_amdgcn_mfma_f32_32x32x16_bf16(kf[s], qf[s], st0, 0, 0, 0);
      st1 = __builtin_amdgcn_mfma_f32_32x32x16_bf16(kf[4 + s], qf[s], st1, 0, 0, 0);
    }
    __builtin_amdgcn_s_setprio(0);

#pragma unroll
    for (int r = 0; r < 16; r++) {
      float a0 = st0[r] * L2E, a1 = st1[r] * L2E;
      float e0, e1;
      asm("v_exp_f32 %0, %1" : "=v"(e0) : "v"(a0));
      asm("v_exp_f32 %0, %1" : "=v"(e1) : "v"(a1));
      st0[r] = e0; st1[r] = e1;
    }
#pragma unroll
    for (int r = 0; r < 16; r += 2) {
      ls0 += st0[r]; ls1 += st0[r + 1];
      ls2 += st1[r]; ls3 += st1[r + 1];
    }

    bf16x8 pfv[4];
#pragma unroll
    for (int t = 0; t < 4; t++) {
      const int c8 = (t & 1) * 8;
      const f32x16& sv = (t < 2) ? st0 : st1;
      uint32_t wA0, wA1, wB0, wB1;
      asm("v_cvt_pk_bf16_f32 %0, %1, %2" : "=v"(wA0) : "v"(sv[c8 + 0]), "v"(sv[c8 + 1]));
      asm("v_cvt_pk_bf16_f32 %0, %1, %2" : "=v"(wA1) : "v"(sv[c8 + 2]), "v"(sv[c8 + 3]));
      asm("v_cvt_pk_bf16_f32 %0, %1, %2" : "=v"(wB0) : "v"(sv[c8 + 4]), "v"(sv[c8 + 5]));
      asm("v_cvt_pk_bf16_f32 %0, %1, %2" : "=v"(wB1) : "v"(sv[c8 + 6]), "v"(sv[c8 + 7]));
      asm("v_permlane32_swap_b32 %0, %1" : "+v"(wA0), "+v"(wB0));
      asm("v_permlane32_swap_b32 %0, %1" : "+v"(wA1), "+v"(wB1));
      union { uint32_t u[4]; bf16x8 v; } pf;
      pf.u[0] = wA0; pf.u[1] = wA1; pf.u[2] = wB0; pf.u[3] = wB1;
      pfv[t] = pf.v;
    }

    bf16x8 vf[8];
#pragma unroll
    for (int r = 0; r < 8; r++)
      vf[r] = *reinterpret_cast<const bf16x8*>(&Vb[p][r * 512 + l * 8]);
    __builtin_amdgcn_s_setprio(1);
#pragma unroll
    for (int t = 0; t < 4; t++) {
      o[0] = __builtin_amdgcn_mfma_f32_32x32x16_bf16(vf[t * 2 + 0], pfv[t], o[0], 0, 0, 0);
      o[1] = __builtin_amdgcn_mfma_f32_32x32x16_bf16(vf[t * 2 + 1], pfv[t], o[1], 0, 0, 0);
    }
    __builtin_amdgcn_s_setprio(0);

    asm volatile("s_waitcnt vmcnt(0)" ::: "memory");
    __syncthreads();
    p ^= 1;
  }

  float lsum = (ls0 + ls1) + (ls2 + ls3);
  lsum += __shfl_xor(lsum, 32);
  const float rl = 1.0f / lsum;
  bf16* orow = Out + (size_t)(b * 1024 + q0 + ql) * 768 + h * 64;
#pragma unroll
  for (int dh = 0; dh < 2; dh++)
#pragma unroll
    for (int rq = 0; rq < 4; rq++) {
      union { ushort us[4]; uint2 v; } pk;
#pragma unroll
      for (int i = 0; i < 4; i++) {
        const bf16 hv = (bf16)(o[dh][rq * 4 + i] * rl);
        pk.us[i] = __builtin_bit_cast(ushort, hv);
      }
      *reinterpret_cast<uint2*>(&orow[dh * 32 + rq * 8 + hi * 4]) = pk.v;
    }
}

// ---------------- launch ------------------------------------------------------
extern "C" void kernel_launch(void* const* d_in, const int* in_sizes, int n_in,
                              void* d_out, int out_size, void* d_ws, size_t ws_size,
                              hipStream_t stream) {
  const float* x = (const float*)d_in[0];
  const float* w_qkv = (const float*)d_in[1];
  const float* w_fc = (const float*)d_in[2];
  const float* b_fc = (const float*)d_in[3];
  float* out = (float*)d_out;
  char* ws = (char*)d_ws;

  bf16* xb = (bf16*)(ws);                    // 8192x768   (dead after gemm<0>)
  bf16* vtb = (bf16*)(ws);                   // 96x64x1024 (aliases xb -- safe)
  bf16* wqkb = (bf16*)(ws + 12582912);       // 2304x768
  bf16* wfcb = (bf16*)(ws + 16121856);       // 768x768
  bf16* qkvb = (bf16*)(ws + 17301504);       // 8192x2304
  bf16* aob = (bf16*)(ws + 55050240);        // 8192x768

  cvt_f32_bf16<<<2048, 256, 0, stream>>>(x, xb, 6291456 / 4);
  cvt_f32_bf16<<<1728, 256, 0, stream>>>(w_qkv, wqkb, 1769472 / 4);
  cvt_f32_bf16<<<576, 256, 0, stream>>>(w_fc, wfcb, 589824 / 4);

  gemm_bt<0><<<dim3(64, 18), 256, 0, stream>>>(xb, wqkb, 8192, 2304, 768,
                                               qkvb, nullptr, nullptr);

  vtrans<<<dim3(96, 16), 256, 0, stream>>>(qkvb, vtb);

  attn_kernel<<<dim3(96, 8), 256, 0, stream>>>(qkvb, vtb, aob);

  gemm_bt<1><<<dim3(64, 6), 256, 0, stream>>>(aob, wfcb, 8192, 768, 768,
                                              nullptr, out, b_fc);
}

// Round 12
// 156.055 us; speedup vs baseline: 1.0218x; 1.0020x over previous
//
#include <hip/hip_runtime.h>
#include <cstdint>
#include <cstddef>

typedef __bf16 bf16;
typedef __bf16 bf16x4 __attribute__((ext_vector_type(4)));
typedef __bf16 bf16x8 __attribute__((ext_vector_type(8)));
typedef float f32x4 __attribute__((ext_vector_type(4)));
typedef float f32x16 __attribute__((ext_vector_type(16)));

typedef const __attribute__((address_space(1))) void* gas_ptr;
typedef __attribute__((address_space(3))) void* las_ptr;

#define GLOAD_LDS16(g, l) __builtin_amdgcn_global_load_lds((gas_ptr)(g), (las_ptr)(l), 16, 0, 0)

// ---------------- f32 -> bf16 convert (vectorized, grid-stride) ----------------
__global__ void cvt_f32_bf16(const float* __restrict__ in, bf16* __restrict__ out, int n4) {
  int i = blockIdx.x * blockDim.x + threadIdx.x;
  int stride = gridDim.x * blockDim.x;
  for (; i < n4; i += stride) {
    float4 v = reinterpret_cast<const float4*>(in)[i];
    bf16x4 o;
    o[0] = (bf16)v.x; o[1] = (bf16)v.y; o[2] = (bf16)v.z; o[3] = (bf16)v.w;
    reinterpret_cast<bf16x4*>(out)[i] = o;
  }
}

// ---------------- GEMM: C[M,N] = A[M,K] * B[N,K]^T  (both K-contiguous) --------
// r12: the r11 vmcnt(4) was erased by __syncthreads() -- HIP semantics emit a
// full s_waitcnt vmcnt(0) lgkmcnt(0) before s_barrier, so the 3-buffer pipe
// degenerated to a per-K-step drain (MfmaUtil stuck at 14%). Fix: RAW
// __builtin_amdgcn_s_barrier() + manual counted s_waitcnt vmcnt(4) +
// sched_barrier(0) fences (T3+T4). Correctness: barrier arrival implies the
// wave's previous-iter ds_reads completed (compiler lgkmcnt waits precede the
// MFMAs issued before the barrier), so post-barrier staging into buffer
// (i+2)%3 == (i-1)%3 cannot race readers; per-wave vmcnt(4)+barrier makes
// buffer p's staging globally visible before any ds_read of p.
template <int MODE>
__global__ __launch_bounds__(256, 3) void gemm_bt(
    const bf16* __restrict__ A, const bf16* __restrict__ B,
    int M, int N, int K,
    bf16* __restrict__ outb, float* __restrict__ outf,
    const float* __restrict__ bias) {
  constexpr int BK = 32;
  __shared__ bf16 ldsA[3][4096];   // 8 slots x 512 elems, triple-buffered
  __shared__ bf16 ldsB[3][4096];
  const int tid = threadIdx.x;
  const int l = tid & 63;
  const int w = tid >> 6;
  const int wr = w >> 1, wc = w & 1;
  const int lr = l & 15, lg = l >> 4;

  // XCD row-chunk swizzle (gx%8==0, nwg%8==0; 64x18 and 64x6 both OK)
  const int gx = gridDim.x;
  const int bid = blockIdx.y * gx + blockIdx.x;
  const int xcd = bid & 7, c = bid >> 3, rpx = gx >> 3;   // rpx = 8
  const int brow = (xcd * rpx + (c & (rpx - 1))) * 128;
  const int bcol = (c / rpx) * 128;

  // staging sources: wave w stages slots {w, 4+w} of A and B.
  const bf16* sa0 = A + (size_t)(brow + w * 16 + lr) * K + lg * 8;
  const bf16* sa1 = sa0 + (size_t)64 * K;
  const bf16* sb0 = B + (size_t)(bcol + w * 16 + lr) * K + lg * 8;
  const bf16* sb1 = sb0 + (size_t)64 * K;
  const int d0 = w * 512 + l * 8;          // LDS elem offset, slot w
  const int d1 = (4 + w) * 512 + l * 8;    // slot 4+w

  f32x4 acc[4][4] = {};

  // prologue: stage k0=0 -> buf0, k0=BK -> buf1  (8 loads in flight per wave)
  GLOAD_LDS16(sa0, &ldsA[0][d0]);
  GLOAD_LDS16(sa1, &ldsA[0][d1]);
  GLOAD_LDS16(sb0, &ldsB[0][d0]);
  GLOAD_LDS16(sb1, &ldsB[0][d1]);
  GLOAD_LDS16(sa0 + BK, &ldsA[1][d0]);
  GLOAD_LDS16(sa1 + BK, &ldsA[1][d1]);
  GLOAD_LDS16(sb0 + BK, &ldsB[1][d0]);
  GLOAD_LDS16(sb1 + BK, &ldsB[1][d1]);

  int p = 0;
  for (int k0 = 0; k0 < K; k0 += BK) {
    // counted wait: newest 4 (next buffer) stay in flight; buffer p complete.
    asm volatile("s_waitcnt vmcnt(4)" ::: "memory");
    __builtin_amdgcn_sched_barrier(0);
    __builtin_amdgcn_s_barrier();          // RAW barrier -- no compiler drain
    __builtin_amdgcn_sched_barrier(0);

    // stage k0+2*BK into the buffer freed at this barrier (dummy on tail)
    int kn = k0 + 2 * BK;
    if (kn >= K) kn = k0;
    const int pt = (p >= 1) ? p - 1 : 2;   // (p+2)%3
    GLOAD_LDS16(sa0 + kn, &ldsA[pt][d0]);
    GLOAD_LDS16(sa1 + kn, &ldsA[pt][d1]);
    GLOAD_LDS16(sb0 + kn, &ldsB[pt][d0]);
    GLOAD_LDS16(sb1 + kn, &ldsB[pt][d1]);

    bf16x8 af[4], bfr[4];
#pragma unroll
    for (int mi = 0; mi < 4; mi++)
      af[mi] = *reinterpret_cast<const bf16x8*>(&ldsA[p][(wr * 4 + mi) * 512 + l * 8]);
#pragma unroll
    for (int ni = 0; ni < 4; ni++)
      bfr[ni] = *reinterpret_cast<const bf16x8*>(&ldsB[p][(wc * 4 + ni) * 512 + l * 8]);
    __builtin_amdgcn_s_setprio(1);
#pragma unroll
    for (int mi = 0; mi < 4; mi++)
#pragma unroll
      for (int ni = 0; ni < 4; ni++)
        acc[mi][ni] = __builtin_amdgcn_mfma_f32_16x16x32_bf16(af[mi], bfr[ni], acc[mi][ni], 0, 0, 0);
    __builtin_amdgcn_s_setprio(0);
    p = (p == 2) ? 0 : p + 1;
  }

  // epilogue: C frag mapping col = lr, row = lg*4 + r  (branch-free row-major)
#pragma unroll
  for (int mi = 0; mi < 4; mi++) {
#pragma unroll
    for (int r = 0; r < 4; r++) {
      const int m = brow + wr * 64 + mi * 16 + lg * 4 + r;
#pragma unroll
      for (int ni = 0; ni < 4; ni++) {
        const int e = bcol + wc * 64 + ni * 16 + lr;
        const float v = acc[mi][ni][r];
        if (MODE == 1) {
          outf[(size_t)m * N + e] = v + bias[e];
        } else {
          outb[(size_t)m * N + e] = (bf16)v;
        }
      }
    }
  }
}

// ---------------- V transpose: qkv cols [1536..2304) -> vtb[96][64][1024] -----
__global__ __launch_bounds__(256) void vtrans(const bf16* __restrict__ qkv,
                                              bf16* __restrict__ vtb) {
  __shared__ bf16 t[64 * 72];
  const int bh = blockIdx.x;          // 0..95
  const int b = bh / 12, h = bh % 12;
  const int nt = blockIdx.y;          // 0..15
  const int tid = threadIdx.x;
#pragma unroll
  for (int it = 0; it < 2; it++) {
    const int item = tid + it * 256;  // 0..511
    const int nl = item >> 3, c = item & 7;
    bf16x8 v = *reinterpret_cast<const bf16x8*>(
        &qkv[(size_t)(b * 1024 + nt * 64 + nl) * 2304 + 1536 + h * 64 + c * 8]);
#pragma unroll
    for (int j = 0; j < 8; j++) t[(c * 8 + j) * 72 + nl] = v[j];
  }
  __syncthreads();
#pragma unroll
  for (int it = 0; it < 2; it++) {
    const int item = tid + it * 256;
    const int d = item >> 3, c2 = item & 7;
    bf16x8 v = *reinterpret_cast<const bf16x8*>(&t[d * 72 + c2 * 8]);
    *reinterpret_cast<bf16x8*>(
        &vtb[(size_t)bh * 65536 + d * 1024 + nt * 64 + c2 * 8]) = v;
  }
}

// ---------------- Flash attention: LDS-staged, fragment-order layout ----------
// (unchanged from r9/r10 -- this structure took attn 99.5 -> ~20 us)
__global__ __launch_bounds__(256, 3) void attn_kernel(
    const bf16* __restrict__ QKV, const bf16* __restrict__ Vt,
    bf16* __restrict__ Out) {
  __shared__ bf16 Kb[2][4096];   // 8KB per buffer, fragment-order
  __shared__ bf16 Vb[2][4096];
  const int tid = threadIdx.x;
  const int l = tid & 63;
  const int w = tid >> 6;
  const int ql = l & 31;
  const int hi = l >> 5;
  const int bh = blockIdx.x;       // 0..95 (head-major -> XCD pinning)
  const int b = bh / 12, h = bh % 12;
  const int q0 = blockIdx.y * 128 + w * 32;
  const bf16* Vh = Vt + (size_t)bh * 65536;
  constexpr float L2E = 1.4426950408889634f;

  const int kdst0 = (0 * 4 + w) * 512 + l * 8;
  const int kdst1 = (1 * 4 + w) * 512 + l * 8;
  const bf16* ksrc0 = QKV + (size_t)(b * 1024 + ql) * 2304 + 768 + h * 64 + w * 16 + hi * 8;
  const bf16* ksrc1 = ksrc0 + (size_t)32 * 2304;
  const bf16* vsrc0 = Vh + (size_t)((w & 1) * 32 + ql) * 1024 + ((0 * 4 + w) >> 1) * 16 + hi * 8;
  const bf16* vsrc1 = Vh + (size_t)((w & 1) * 32 + ql) * 1024 + ((1 * 4 + w) >> 1) * 16 + hi * 8;

  const bf16* Qrow = QKV + (size_t)(b * 1024 + q0 + ql) * 2304 + h * 64;
  bf16x8 qf[4];
#pragma unroll
  for (int s = 0; s < 4; s++)
    qf[s] = *reinterpret_cast<const bf16x8*>(&Qrow[s * 16 + hi * 8]);

  f32x16 o[2] = {};
  float ls0 = 0.f, ls1 = 0.f, ls2 = 0.f, ls3 = 0.f;

  GLOAD_LDS16(ksrc0, &Kb[0][kdst0]);
  GLOAD_LDS16(ksrc1, &Kb[0][kdst1]);
  GLOAD_LDS16(vsrc0, &Vb[0][kdst0]);
  GLOAD_LDS16(vsrc1, &Vb[0][kdst1]);
  asm volatile("s_waitcnt vmcnt(0)" ::: "memory");
  __syncthreads();

  int p = 0;
  for (int it = 0; it < 16; ++it) {
    const int kt = it * 64;
    if (it < 15) {
      GLOAD_LDS16(ksrc0 + (size_t)(kt + 64) * 2304, &Kb[p ^ 1][kdst0]);
      GLOAD_LDS16(ksrc1 + (size_t)(kt + 64) * 2304, &Kb[p ^ 1][kdst1]);
      GLOAD_LDS16(vsrc0 + (kt + 64), &Vb[p ^ 1][kdst0]);
      GLOAD_LDS16(vsrc1 + (kt + 64), &Vb[p ^ 1][kdst1]);
    }

    bf16x8 kf[8];
#pragma unroll
    for (int r = 0; r < 8; r++)
      kf[r] = *reinterpret_cast<const bf16x8*>(&Kb[p][r * 512 + l * 8]);
    f32x16 st0 = {}, st1 = {};
    __builtin_amdgcn_s_setprio(1);
#pragma unroll
    for (int s = 0; s < 4; s++) {
      st0 = __builtin_amdgcn_mfma_f32_32x32x16_bf16(kf[s], qf[s], st0, 0, 0, 0);
      st1 = __builtin_amdgcn_mfma_f32_32x32x16_bf16(kf[4 + s], qf[s], st1, 0, 0, 0);
    }
    __builtin_amdgcn_s_setprio(0);

#pragma unroll
    for (int r = 0; r < 16; r++) {
      float a0 = st0[r] * L2E, a1 = st1[r] * L2E;
      float e0, e1;
      asm("v_exp_f32 %0, %1" : "=v"(e0) : "v"(a0));
      asm("v_exp_f32 %0, %1" : "=v"(e1) : "v"(a1));
      st0[r] = e0; st1[r] = e1;
    }
#pragma unroll
    for (int r = 0; r < 16; r += 2) {
      ls0 += st0[r]; ls1 += st0[r + 1];
      ls2 += st1[r]; ls3 += st1[r + 1];
    }

    bf16x8 pfv[4];
#pragma unroll
    for (int t = 0; t < 4; t++) {
      const int c8 = (t & 1) * 8;
      const f32x16& sv = (t < 2) ? st0 : st1;
      uint32_t wA0, wA1, wB0, wB1;
      asm("v_cvt_pk_bf16_f32 %0, %1, %2" : "=v"(wA0) : "v"(sv[c8 + 0]), "v"(sv[c8 + 1]));
      asm("v_cvt_pk_bf16_f32 %0, %1, %2" : "=v"(wA1) : "v"(sv[c8 + 2]), "v"(sv[c8 + 3]));
      asm("v_cvt_pk_bf16_f32 %0, %1, %2" : "=v"(wB0) : "v"(sv[c8 + 4]), "v"(sv[c8 + 5]));
      asm("v_cvt_pk_bf16_f32 %0, %1, %2" : "=v"(wB1) : "v"(sv[c8 + 6]), "v"(sv[c8 + 7]));
      asm("v_permlane32_swap_b32 %0, %1" : "+v"(wA0), "+v"(wB0));
      asm("v_permlane32_swap_b32 %0, %1" : "+v"(wA1), "+v"(wB1));
      union { uint32_t u[4]; bf16x8 v; } pf;
      pf.u[0] = wA0; pf.u[1] = wA1; pf.u[2] = wB0; pf.u[3] = wB1;
      pfv[t] = pf.v;
    }

    bf16x8 vf[8];
#pragma unroll
    for (int r = 0; r < 8; r++)
      vf[r] = *reinterpret_cast<const bf16x8*>(&Vb[p][r * 512 + l * 8]);
    __builtin_amdgcn_s_setprio(1);
#pragma unroll
    for (int t = 0; t < 4; t++) {
      o[0] = __builtin_amdgcn_mfma_f32_32x32x16_bf16(vf[t * 2 + 0], pfv[t], o[0], 0, 0, 0);
      o[1] = __builtin_amdgcn_mfma_f32_32x32x16_bf16(vf[t * 2 + 1], pfv[t], o[1], 0, 0, 0);
    }
    __builtin_amdgcn_s_setprio(0);

    asm volatile("s_waitcnt vmcnt(0)" ::: "memory");
    __syncthreads();
    p ^= 1;
  }

  float lsum = (ls0 + ls1) + (ls2 + ls3);
  lsum += __shfl_xor(lsum, 32);
  const float rl = 1.0f / lsum;
  bf16* orow = Out + (size_t)(b * 1024 + q0 + ql) * 768 + h * 64;
#pragma unroll
  for (int dh = 0; dh < 2; dh++)
#pragma unroll
    for (int rq = 0; rq < 4; rq++) {
      union { ushort us[4]; uint2 v; } pk;
#pragma unroll
      for (int i = 0; i < 4; i++) {
        const bf16 hv = (bf16)(o[dh][rq * 4 + i] * rl);
        pk.us[i] = __builtin_bit_cast(ushort, hv);
      }
      *reinterpret_cast<uint2*>(&orow[dh * 32 + rq * 8 + hi * 4]) = pk.v;
    }
}

// ---------------- launch ------------------------------------------------------
extern "C" void kernel_launch(void* const* d_in, const int* in_sizes, int n_in,
                              void* d_out, int out_size, void* d_ws, size_t ws_size,
                              hipStream_t stream) {
  const float* x = (const float*)d_in[0];
  const float* w_qkv = (const float*)d_in[1];
  const float* w_fc = (const float*)d_in[2];
  const float* b_fc = (const float*)d_in[3];
  float* out = (float*)d_out;
  char* ws = (char*)d_ws;

  bf16* xb = (bf16*)(ws);                    // 8192x768   (dead after gemm<0>)
  bf16* vtb = (bf16*)(ws);                   // 96x64x1024 (aliases xb -- safe)
  bf16* wqkb = (bf16*)(ws + 12582912);       // 2304x768
  bf16* wfcb = (bf16*)(ws + 16121856);       // 768x768
  bf16* qkvb = (bf16*)(ws + 17301504);       // 8192x2304
  bf16* aob = (bf16*)(ws + 55050240);        // 8192x768

  cvt_f32_bf16<<<2048, 256, 0, stream>>>(x, xb, 6291456 / 4);
  cvt_f32_bf16<<<1728, 256, 0, stream>>>(w_qkv, wqkb, 1769472 / 4);
  cvt_f32_bf16<<<576, 256, 0, stream>>>(w_fc, wfcb, 589824 / 4);

  gemm_bt<0><<<dim3(64, 18), 256, 0, stream>>>(xb, wqkb, 8192, 2304, 768,
                                               qkvb, nullptr, nullptr);

  vtrans<<<dim3(96, 16), 256, 0, stream>>>(qkvb, vtb);

  attn_kernel<<<dim3(96, 8), 256, 0, stream>>>(qkvb, vtb, aob);

  gemm_bt<1><<<dim3(64, 6), 256, 0, stream>>>(aob, wfcb, 8192, 768, 768,
                                              nullptr, out, b_fc);
}

// Round 13
// 144.993 us; speedup vs baseline: 1.0998x; 1.0763x over previous
//
#include <hip/hip_runtime.h>
#include <cstdint>
#include <cstddef>

typedef __bf16 bf16;
typedef __bf16 bf16x4 __attribute__((ext_vector_type(4)));
typedef __bf16 bf16x8 __attribute__((ext_vector_type(8)));
typedef float f32x4 __attribute__((ext_vector_type(4)));
typedef float f32x16 __attribute__((ext_vector_type(16)));

typedef const __attribute__((address_space(1))) void* gas_ptr;
typedef __attribute__((address_space(3))) void* las_ptr;

#define GLOAD_LDS16(g, l) __builtin_amdgcn_global_load_lds((gas_ptr)(g), (las_ptr)(l), 16, 0, 0)

// ---------------- f32 -> bf16 convert (vectorized, grid-stride) ----------------
__global__ void cvt_f32_bf16(const float* __restrict__ in, bf16* __restrict__ out, int n4) {
  int i = blockIdx.x * blockDim.x + threadIdx.x;
  int stride = gridDim.x * blockDim.x;
  for (; i < n4; i += stride) {
    float4 v = reinterpret_cast<const float4*>(in)[i];
    bf16x4 o;
    o[0] = (bf16)v.x; o[1] = (bf16)v.y; o[2] = (bf16)v.z; o[3] = (bf16)v.w;
    reinterpret_cast<bf16x4*>(out)[i] = o;
  }
}

// ---------------- GEMM: C[M,N] = A[M,K] * B[N,K]^T  (both K-contiguous) --------
// r13: 128x128 structure was at its shape-adjusted ceiling (~414 TF at K=768,
// consistent with the m102 curve). Reshape: BM=256 x BN=128, 8 waves (512 thr),
// wave tile 64x64 (same per-wave code/VGPR as before -> no spill risk):
//  * 16 waves/CU (2 blocks x 8 waves at 72KB LDS) vs 8 before: 2x TLP to hide
//    the per-step latency that was the measured binding constraint.
//  * 576 blocks QKV (~1.1 rounds vs 2.25), 192 FC (1 round).
//  * 3 gload_lds/thread/step (vs 4); barrier cost per FLOP halved.
//  * triple-buffer + counted vmcnt(3) + RAW s_barrier kept; setprio DROPPED
//    (m190: harmful in barrier-lockstep GEMM).
// Fragment-order LDS: A slots 0..15 (16 rows each), B slots 0..7; slot r
// lane l at elem r*512+l*8 -> ds_read_b128 lane-linear, zero conflicts.
template <int MODE>
__global__ __launch_bounds__(512, 4) void gemm_bt(
    const bf16* __restrict__ A, const bf16* __restrict__ B,
    int M, int N, int K,
    bf16* __restrict__ outb, float* __restrict__ outf,
    const float* __restrict__ bias) {
  constexpr int BK = 32;
  __shared__ bf16 lds[3][12288];   // per buffer: A 16x512 elems | B 8x512 elems
  const int tid = threadIdx.x;
  const int l = tid & 63;
  const int w = tid >> 6;          // 0..7
  const int wr = w >> 1, wc = w & 1;
  const int lr = l & 15, lg = l >> 4;

  // XCD row-chunk swizzle: 32 row-tiles, 4 per XCD; col-major within chunk.
  // (nwg = 32*gridDim.y, divisible by 8 for gy=18 and gy=6.)
  const int bid = blockIdx.y * 32 + blockIdx.x;
  const int xcd = bid & 7, c = bid >> 3;
  const int brow = (xcd * 4 + (c & 3)) * 256;
  const int bcol = (c >> 2) * 128;

  // staging: wave w stages A slots {w, 8+w} and B slot w (3 loads/thread/step)
  const bf16* sa0 = A + (size_t)(brow + w * 16 + lr) * K + lg * 8;
  const bf16* sa1 = sa0 + (size_t)128 * K;
  const bf16* sb0 = B + (size_t)(bcol + w * 16 + lr) * K + lg * 8;
  const int dA0 = w * 512 + l * 8;
  const int dA1 = (8 + w) * 512 + l * 8;
  const int dB0 = 8192 + w * 512 + l * 8;

  f32x4 acc[4][4] = {};

  // prologue: stage k0=0 -> buf0, k0=BK -> buf1 (6 loads in flight per thread)
  GLOAD_LDS16(sa0, &lds[0][dA0]);
  GLOAD_LDS16(sa1, &lds[0][dA1]);
  GLOAD_LDS16(sb0, &lds[0][dB0]);
  GLOAD_LDS16(sa0 + BK, &lds[1][dA0]);
  GLOAD_LDS16(sa1 + BK, &lds[1][dA1]);
  GLOAD_LDS16(sb0 + BK, &lds[1][dB0]);

  int p = 0;
  for (int k0 = 0; k0 < K; k0 += BK) {
    // counted wait: newest 3 (next buffer) stay in flight; buffer p complete.
    asm volatile("s_waitcnt vmcnt(3)" ::: "memory");
    __builtin_amdgcn_sched_barrier(0);
    __builtin_amdgcn_s_barrier();          // RAW barrier -- no compiler drain
    __builtin_amdgcn_sched_barrier(0);

    // stage k0+2*BK into the buffer freed at this barrier (dummy on tail)
    int kn = k0 + 2 * BK;
    if (kn >= K) kn = k0;
    const int pt = (p >= 1) ? p - 1 : 2;   // (p+2)%3
    GLOAD_LDS16(sa0 + kn, &lds[pt][dA0]);
    GLOAD_LDS16(sa1 + kn, &lds[pt][dA1]);
    GLOAD_LDS16(sb0 + kn, &lds[pt][dB0]);

    bf16x8 af[4], bfr[4];
#pragma unroll
    for (int mi = 0; mi < 4; mi++)
      af[mi] = *reinterpret_cast<const bf16x8*>(&lds[p][(wr * 4 + mi) * 512 + l * 8]);
#pragma unroll
    for (int ni = 0; ni < 4; ni++)
      bfr[ni] = *reinterpret_cast<const bf16x8*>(&lds[p][8192 + (wc * 4 + ni) * 512 + l * 8]);
#pragma unroll
    for (int mi = 0; mi < 4; mi++)
#pragma unroll
      for (int ni = 0; ni < 4; ni++)
        acc[mi][ni] = __builtin_amdgcn_mfma_f32_16x16x32_bf16(af[mi], bfr[ni], acc[mi][ni], 0, 0, 0);
    p = (p == 2) ? 0 : p + 1;
  }

  // epilogue: C frag mapping col = lr, row = lg*4 + r  (branch-free row-major)
#pragma unroll
  for (int mi = 0; mi < 4; mi++) {
#pragma unroll
    for (int r = 0; r < 4; r++) {
      const int m = brow + wr * 64 + mi * 16 + lg * 4 + r;
#pragma unroll
      for (int ni = 0; ni < 4; ni++) {
        const int e = bcol + wc * 64 + ni * 16 + lr;
        const float v = acc[mi][ni][r];
        if (MODE == 1) {
          outf[(size_t)m * N + e] = v + bias[e];
        } else {
          outb[(size_t)m * N + e] = (bf16)v;
        }
      }
    }
  }
}

// ---------------- V transpose: qkv cols [1536..2304) -> vtb[96][64][1024] -----
__global__ __launch_bounds__(256) void vtrans(const bf16* __restrict__ qkv,
                                              bf16* __restrict__ vtb) {
  __shared__ bf16 t[64 * 72];
  const int bh = blockIdx.x;          // 0..95
  const int b = bh / 12, h = bh % 12;
  const int nt = blockIdx.y;          // 0..15
  const int tid = threadIdx.x;
#pragma unroll
  for (int it = 0; it < 2; it++) {
    const int item = tid + it * 256;  // 0..511
    const int nl = item >> 3, c = item & 7;
    bf16x8 v = *reinterpret_cast<const bf16x8*>(
        &qkv[(size_t)(b * 1024 + nt * 64 + nl) * 2304 + 1536 + h * 64 + c * 8]);
#pragma unroll
    for (int j = 0; j < 8; j++) t[(c * 8 + j) * 72 + nl] = v[j];
  }
  __syncthreads();
#pragma unroll
  for (int it = 0; it < 2; it++) {
    const int item = tid + it * 256;
    const int d = item >> 3, c2 = item & 7;
    bf16x8 v = *reinterpret_cast<const bf16x8*>(&t[d * 72 + c2 * 8]);
    *reinterpret_cast<bf16x8*>(
        &vtb[(size_t)bh * 65536 + d * 1024 + nt * 64 + c2 * 8]) = v;
  }
}

// ---------------- Flash attention: LDS-staged, fragment-order layout ----------
// (unchanged from r9 -- this structure took attn 99.5 -> ~20 us)
__global__ __launch_bounds__(256, 3) void attn_kernel(
    const bf16* __restrict__ QKV, const bf16* __restrict__ Vt,
    bf16* __restrict__ Out) {
  __shared__ bf16 Kb[2][4096];   // 8KB per buffer, fragment-order
  __shared__ bf16 Vb[2][4096];
  const int tid = threadIdx.x;
  const int l = tid & 63;
  const int w = tid >> 6;
  const int ql = l & 31;
  const int hi = l >> 5;
  const int bh = blockIdx.x;       // 0..95 (head-major -> XCD pinning)
  const int b = bh / 12, h = bh % 12;
  const int q0 = blockIdx.y * 128 + w * 32;
  const bf16* Vh = Vt + (size_t)bh * 65536;
  constexpr float L2E = 1.4426950408889634f;

  const int kdst0 = (0 * 4 + w) * 512 + l * 8;
  const int kdst1 = (1 * 4 + w) * 512 + l * 8;
  const bf16* ksrc0 = QKV + (size_t)(b * 1024 + ql) * 2304 + 768 + h * 64 + w * 16 + hi * 8;
  const bf16* ksrc1 = ksrc0 + (size_t)32 * 2304;
  const bf16* vsrc0 = Vh + (size_t)((w & 1) * 32 + ql) * 1024 + ((0 * 4 + w) >> 1) * 16 + hi * 8;
  const bf16* vsrc1 = Vh + (size_t)((w & 1) * 32 + ql) * 1024 + ((1 * 4 + w) >> 1) * 16 + hi * 8;

  const bf16* Qrow = QKV + (size_t)(b * 1024 + q0 + ql) * 2304 + h * 64;
  bf16x8 qf[4];
#pragma unroll
  for (int s = 0; s < 4; s++)
    qf[s] = *reinterpret_cast<const bf16x8*>(&Qrow[s * 16 + hi * 8]);

  f32x16 o[2] = {};
  float ls0 = 0.f, ls1 = 0.f, ls2 = 0.f, ls3 = 0.f;

  GLOAD_LDS16(ksrc0, &Kb[0][kdst0]);
  GLOAD_LDS16(ksrc1, &Kb[0][kdst1]);
  GLOAD_LDS16(vsrc0, &Vb[0][kdst0]);
  GLOAD_LDS16(vsrc1, &Vb[0][kdst1]);
  asm volatile("s_waitcnt vmcnt(0)" ::: "memory");
  __syncthreads();

  int p = 0;
  for (int it = 0; it < 16; ++it) {
    const int kt = it * 64;
    if (it < 15) {
      GLOAD_LDS16(ksrc0 + (size_t)(kt + 64) * 2304, &Kb[p ^ 1][kdst0]);
      GLOAD_LDS16(ksrc1 + (size_t)(kt + 64) * 2304, &Kb[p ^ 1][kdst1]);
      GLOAD_LDS16(vsrc0 + (kt + 64), &Vb[p ^ 1][kdst0]);
      GLOAD_LDS16(vsrc1 + (kt + 64), &Vb[p ^ 1][kdst1]);
    }

    bf16x8 kf[8];
#pragma unroll
    for (int r = 0; r < 8; r++)
      kf[r] = *reinterpret_cast<const bf16x8*>(&Kb[p][r * 512 + l * 8]);
    f32x16 st0 = {}, st1 = {};
    __builtin_amdgcn_s_setprio(1);
#pragma unroll
    for (int s = 0; s < 4; s++) {
      st0 = __builtin_amdgcn_mfma_f32_32x32x16_bf16(kf[s], qf[s], st0, 0, 0, 0);
      st1 = __builtin_amdgcn_mfma_f32_32x32x16_bf16(kf[4 + s], qf[s], st1, 0, 0, 0);
    }
    __builtin_amdgcn_s_setprio(0);

#pragma unroll
    for (int r = 0; r < 16; r++) {
      float a0 = st0[r] * L2E, a1 = st1[r] * L2E;
      float e0, e1;
      asm("v_exp_f32 %0, %1" : "=v"(e0) : "v"(a0));
      asm("v_exp_f32 %0, %1" : "=v"(e1) : "v"(a1));
      st0[r] = e0; st1[r] = e1;
    }
#pragma unroll
    for (int r = 0; r < 16; r += 2) {
      ls0 += st0[r]; ls1 += st0[r + 1];
      ls2 += st1[r]; ls3 += st1[r + 1];
    }

    bf16x8 pfv[4];
#pragma unroll
    for (int t = 0; t < 4; t++) {
      const int c8 = (t & 1) * 8;
      const f32x16& sv = (t < 2) ? st0 : st1;
      uint32_t wA0, wA1, wB0, wB1;
      asm("v_cvt_pk_bf16_f32 %0, %1, %2" : "=v"(wA0) : "v"(sv[c8 + 0]), "v"(sv[c8 + 1]));
      asm("v_cvt_pk_bf16_f32 %0, %1, %2" : "=v"(wA1) : "v"(sv[c8 + 2]), "v"(sv[c8 + 3]));
      asm("v_cvt_pk_bf16_f32 %0, %1, %2" : "=v"(wB0) : "v"(sv[c8 + 4]), "v"(sv[c8 + 5]));
      asm("v_cvt_pk_bf16_f32 %0, %1, %2" : "=v"(wB1) : "v"(sv[c8 + 6]), "v"(sv[c8 + 7]));
      asm("v_permlane32_swap_b32 %0, %1" : "+v"(wA0), "+v"(wB0));
      asm("v_permlane32_swap_b32 %0, %1" : "+v"(wA1), "+v"(wB1));
      union { uint32_t u[4]; bf16x8 v; } pf;
      pf.u[0] = wA0; pf.u[1] = wA1; pf.u[2] = wB0; pf.u[3] = wB1;
      pfv[t] = pf.v;
    }

    bf16x8 vf[8];
#pragma unroll
    for (int r = 0; r < 8; r++)
      vf[r] = *reinterpret_cast<const bf16x8*>(&Vb[p][r * 512 + l * 8]);
    __builtin_amdgcn_s_setprio(1);
#pragma unroll
    for (int t = 0; t < 4; t++) {
      o[0] = __builtin_amdgcn_mfma_f32_32x32x16_bf16(vf[t * 2 + 0], pfv[t], o[0], 0, 0, 0);
      o[1] = __builtin_amdgcn_mfma_f32_32x32x16_bf16(vf[t * 2 + 1], pfv[t], o[1], 0, 0, 0);
    }
    __builtin_amdgcn_s_setprio(0);

    asm volatile("s_waitcnt vmcnt(0)" ::: "memory");
    __syncthreads();
    p ^= 1;
  }

  float lsum = (ls0 + ls1) + (ls2 + ls3);
  lsum += __shfl_xor(lsum, 32);
  const float rl = 1.0f / lsum;
  bf16* orow = Out + (size_t)(b * 1024 + q0 + ql) * 768 + h * 64;
#pragma unroll
  for (int dh = 0; dh < 2; dh++)
#pragma unroll
    for (int rq = 0; rq < 4; rq++) {
      union { ushort us[4]; uint2 v; } pk;
#pragma unroll
      for (int i = 0; i < 4; i++) {
        const bf16 hv = (bf16)(o[dh][rq * 4 + i] * rl);
        pk.us[i] = __builtin_bit_cast(ushort, hv);
      }
      *reinterpret_cast<uint2*>(&orow[dh * 32 + rq * 8 + hi * 4]) = pk.v;
    }
}

// ---------------- launch ------------------------------------------------------
extern "C" void kernel_launch(void* const* d_in, const int* in_sizes, int n_in,
                              void* d_out, int out_size, void* d_ws, size_t ws_size,
                              hipStream_t stream) {
  const float* x = (const float*)d_in[0];
  const float* w_qkv = (const float*)d_in[1];
  const float* w_fc = (const float*)d_in[2];
  const float* b_fc = (const float*)d_in[3];
  float* out = (float*)d_out;
  char* ws = (char*)d_ws;

  bf16* xb = (bf16*)(ws);                    // 8192x768   (dead after gemm<0>)
  bf16* vtb = (bf16*)(ws);                   // 96x64x1024 (aliases xb -- safe)
  bf16* wqkb = (bf16*)(ws + 12582912);       // 2304x768
  bf16* wfcb = (bf16*)(ws + 16121856);       // 768x768
  bf16* qkvb = (bf16*)(ws + 17301504);       // 8192x2304
  bf16* aob = (bf16*)(ws + 55050240);        // 8192x768

  cvt_f32_bf16<<<2048, 256, 0, stream>>>(x, xb, 6291456 / 4);
  cvt_f32_bf16<<<1728, 256, 0, stream>>>(w_qkv, wqkb, 1769472 / 4);
  cvt_f32_bf16<<<576, 256, 0, stream>>>(w_fc, wfcb, 589824 / 4);

  gemm_bt<0><<<dim3(32, 18), 512, 0, stream>>>(xb, wqkb, 8192, 2304, 768,
                                               qkvb, nullptr, nullptr);

  vtrans<<<dim3(96, 16), 256, 0, stream>>>(qkvb, vtb);

  attn_kernel<<<dim3(96, 8), 256, 0, stream>>>(qkvb, vtb, aob);

  gemm_bt<1><<<dim3(32, 6), 512, 0, stream>>>(aob, wfcb, 8192, 768, 768,
                                              nullptr, out, b_fc);
}